// Round 11
// baseline (457.064 us; speedup 1.0000x reference)
//
#include <hip/hip_runtime.h>

// Round 11: flash restructured for LDS-operand reuse: 64 q-rows/wave (each K/V
// fragment read once, used for two MFMAs), 4 waves x 64q = 256 q/block,
// grid 256 = 1 block/CU, K+V double-buffered in 128KB LDS, ONE barrier/tile.
// Rest of pipeline = r7.

typedef _Float16 f16;
typedef _Float16 h8_t  __attribute__((ext_vector_type(8)));
typedef _Float16 h4_t  __attribute__((ext_vector_type(4)));
typedef float    f4_t  __attribute__((ext_vector_type(4)));
typedef float    f16x  __attribute__((ext_vector_type(16)));
typedef unsigned int u4_t  __attribute__((ext_vector_type(4)));

#define LOG2E 1.4426950408889634f

__device__ __forceinline__ void llds16(const f16* g, f16* s) {
    __builtin_amdgcn_global_load_lds(
        (const __attribute__((address_space(1))) void*)g,
        (__attribute__((address_space(3))) void*)s, 16, 0, 0);
}
__device__ __forceinline__ unsigned int pk2(float a, float b) {
    auto h = __builtin_amdgcn_cvt_pkrtz(a, b);
    return __builtin_bit_cast(unsigned int, h);
}

// ---------------- prep: weights f32->f16 (+W1 combine). 288 blocks.
__global__ __launch_bounds__(256)
void prep(const float* __restrict__ Wa, const float* __restrict__ Wg,
          const float* __restrict__ W1, const float* __restrict__ W2,
          f16* __restrict__ oa, f16* __restrict__ og,
          f16* __restrict__ o1c, f16* __restrict__ o2)
{
    int i = blockIdx.x * 256 + threadIdx.x;   // quad index; total 73728
    if (i < 40960) {
        const float* s; f16* d; int off;
        if (i < 16384)      { s = Wa; d = oa; off = i; }
        else if (i < 32768) { s = Wg; d = og; off = i - 16384; }
        else                { s = W2; d = o2; off = i - 32768; }
        f4_t v = ((const f4_t*)s)[off];
        h4_t h;
        h[0]=(f16)v[0]; h[1]=(f16)v[1]; h[2]=(f16)v[2]; h[3]=(f16)v[3];
        ((h4_t*)d)[off] = h;
    } else {
        int off = i - 40960;                  // W1comb [256][512]
        int j = off >> 7, c0 = (off & 127) * 4;
        const float* r = W1 + (size_t)j * 768;
        f4_t v0, v1;
        if (c0 < 256) { v0 = *(const f4_t*)(r + c0); v1 = *(const f4_t*)(r + 512 + c0); }
        else          { v0 = *(const f4_t*)(r + c0); v1 = *(const f4_t*)(r + 256 + c0); }
        h4_t h;
        #pragma unroll
        for (int e = 0; e < 4; e++)
            h[e] = (f16)(c0 < 256 ? v0[e] + v1[e] : v0[e] - v1[e]);
        ((h4_t*)o1c)[off] = h;
    }
}

// ---------------- both projections in one launch; z=1 (anchor) bn==0 emits VT
__global__ __launch_bounds__(256)
void proj_pair(const float* __restrict__ guess, const float* __restrict__ anchor,
               const f16* __restrict__ WG, const f16* __restrict__ WA,
               const float* __restrict__ bg, const float* __restrict__ ba,
               f16* __restrict__ GE, f16* __restrict__ AC,
               f16* __restrict__ vt)
{
    constexpr int BK = 32, LDA = 40, LDB = 40;
    __shared__ f16 As[64 * LDA];
    __shared__ f16 Bs[128 * LDB];
    const int t = threadIdx.x;
    const int w = t >> 6, l = t & 63, lg = l >> 4, lr = l & 15;
    const int bm = blockIdx.x, bn = blockIdx.y, z = blockIdx.z;
    const float* A   = z ? anchor : guess;
    const f16*   B   = z ? WA : WG;
    const float* bias= z ? ba : bg;
    const float scale= z ? 1.0f : LOG2E;
    f16* C = z ? AC : GE;
    f4_t acc[4][2] = {};

    for (int kt = 0; kt < 256; kt += BK) {
        {   // A tile 64x32, f32 -> f16
            int row = t >> 2, c8 = (t & 3) * 8;
            const float* Af = A + (size_t)(bm * 64 + row) * 256 + kt + c8;
            f4_t v0 = *(const f4_t*)Af;
            f4_t v1 = *(const f4_t*)(Af + 4);
            h8_t h;
            h[0]=(f16)v0[0]; h[1]=(f16)v0[1]; h[2]=(f16)v0[2]; h[3]=(f16)v0[3];
            h[4]=(f16)v1[0]; h[5]=(f16)v1[1]; h[6]=(f16)v1[2]; h[7]=(f16)v1[3];
            *(h8_t*)(&As[row * LDA + c8]) = h;
        }
        {   // B tile 128x32
            int s0 = t, row = s0 >> 2, c8 = (s0 & 3) * 8;
            *(u4_t*)(&Bs[row * LDB + c8]) =
                *(const u4_t*)(B + (size_t)(bn * 128 + row) * 256 + kt + c8);
            int s1 = t + 256; row = s1 >> 2; c8 = (s1 & 3) * 8;
            *(u4_t*)(&Bs[row * LDB + c8]) =
                *(const u4_t*)(B + (size_t)(bn * 128 + row) * 256 + kt + c8);
        }
        __syncthreads();
        h8_t af[4], bf[2];
        #pragma unroll
        for (int mf = 0; mf < 4; mf++)
            af[mf] = *(const h8_t*)(&As[(mf * 16 + lr) * LDA + lg * 8]);
        #pragma unroll
        for (int nf = 0; nf < 2; nf++)
            bf[nf] = *(const h8_t*)(&Bs[(w * 32 + nf * 16 + lr) * LDB + lg * 8]);
        #pragma unroll
        for (int mf = 0; mf < 4; mf++)
            #pragma unroll
            for (int nf = 0; nf < 2; nf++)
                acc[mf][nf] = __builtin_amdgcn_mfma_f32_16x16x32_f16(
                    af[mf], bf[nf], acc[mf][nf], 0, 0, 0);
        // fused anchor^T emit (z==1, bn==0 only; As holds anchor f16 tile)
        if (z == 1 && bn == 0) {
            const int c = t >> 3, r0 = (t & 7) * 8;
            h8_t h;
            #pragma unroll
            for (int j = 0; j < 8; j++) h[j] = As[(r0 + j) * LDA + c];
            *(h8_t*)(vt + (size_t)(kt + c) * 8192 + bm * 64 + r0) = h;
        }
        __syncthreads();
    }

    #pragma unroll
    for (int mf = 0; mf < 4; mf++)
        #pragma unroll
        for (int nf = 0; nf < 2; nf++)
            #pragma unroll
            for (int r = 0; r < 4; r++) {
                int row = bm * 64 + mf * 16 + lg * 4 + r;
                int col = bn * 128 + w * 32 + nf * 16 + lr;
                C[(size_t)row * 256 + col] = (f16)((acc[mf][nf][r] + bias[col]) * scale);
            }
}

// ------------------------------------------------------------- flash attention
// 64 q/wave (two 32-q halves share every K/V fragment read), 256 q/block,
// grid 256 (sl=bid&7 XCD-pinned, qb=bid>>3), K/V double-buffered, 1 barrier/tile.
__global__ __launch_bounds__(256, 1)
void flash_attn(const f16* __restrict__ Q, const f16* __restrict__ Kc,
                const f16* __restrict__ Vt, f16* __restrict__ OPN,
                float* __restrict__ mpart, float* __restrict__ lpart)
{
    constexpr int D = 256, BK = 64, NK = 8192, SL = 1024, NT = SL / BK;
    __shared__ f16 Ks0[BK * D];  __shared__ f16 Vs0[D * BK];   // 32 KB each
    __shared__ f16 Ks1[BK * D];  __shared__ f16 Vs1[D * BK];   // 128 KB total
    const int t = threadIdx.x, w = t >> 6, l = t & 63;
    const int q = l & 31, hi = l >> 5;
    const int sl = blockIdx.x & 7, qb = blockIdx.x >> 3;
    const int k0b = sl * SL;
    const int qg0 = qb * 256 + w * 64;

    // Q fragments for both 32-q halves (128 VGPR)
    h8_t qfA[16], qfB[16];
    {
        const f16* qrA = Q + (size_t)(qg0 + q) * D + hi * 8;
        const f16* qrB = qrA + (size_t)32 * D;
        #pragma unroll
        for (int ks = 0; ks < 16; ks++) {
            qfA[ks] = *(const h8_t*)(qrA + ks * 16);
            qfB[ks] = *(const h8_t*)(qrB + ks * 16);
        }
    }

    // staging lane constants (inverse-swizzled global source, linear LDS dest)
    const int sK0 = ((t & 31) ^ (t >> 5)) << 3;
    const int sx  = (t & 15) ^ (t >> 4);
    const int dV  = (t >> 4) * 2 + (sx >> 3);
    const int cV  = (sx & 7) << 3;

    auto stage = [&](int k0, f16* kd, f16* vd) {
        #pragma unroll
        for (int i = 0; i < 8; i++) {
            const f16* g = Kc + (size_t)(k0 + i * 8 + (t >> 5)) * D + (sK0 ^ ((i & 1) << 6));
            llds16(g, kd + i * 2048 + w * 512);
        }
        #pragma unroll
        for (int i = 0; i < 8; i++) {
            const f16* g = Vt + (size_t)(i * 32 + dV) * NK + k0 + cV;
            llds16(g, vd + i * 2048 + w * 512);
        }
    };

    stage(k0b, Ks0, Vs0);
    __syncthreads();

    f16x oA[8] = {}, oB[8] = {};
    float mA = -1e30f, lA = 0.f, mB = -1e30f, lB = 0.f;
    const int rswzK = (q & 15) << 4;
    const int kbase0 = q * 512;
    const int vbase  = (q >> 1) * 256;
    const int vswz   = (q >> 1) << 4;
    const int vcol0  = ((q & 1) << 7) | (hi << 4);

    auto softmax = [&](f16x& s0, f16x& s1, f16x (&o)[8], float& m_run, float& l_run) {
        float mt = s0[0];
        #pragma unroll
        for (int r = 1; r < 16; r++) mt = fmaxf(mt, s0[r]);
        #pragma unroll
        for (int r = 0; r < 16; r++) mt = fmaxf(mt, s1[r]);
        mt = fmaxf(mt, __shfl_xor(mt, 32));
        if (!__all(mt <= m_run + 8.0f)) {
            const float mnew = fmaxf(m_run, mt);
            const float corr = exp2f(m_run - mnew);
            #pragma unroll
            for (int r = 0; r < 16; r++) {
                const float c = __shfl(corr, (r & 3) + 8 * (r >> 2) + 4 * hi);
                #pragma unroll
                for (int nb = 0; nb < 8; nb++) o[nb][r] *= c;
            }
            l_run *= corr;
            m_run = mnew;
        }
        float rs = 0.f;
        #pragma unroll
        for (int r = 0; r < 16; r++) { s0[r] = exp2f(s0[r] - m_run); rs += s0[r]; }
        #pragma unroll
        for (int r = 0; r < 16; r++) { s1[r] = exp2f(s1[r] - m_run); rs += s1[r]; }
        rs += __shfl_xor(rs, 32);
        l_run += rs;
    };

    auto tile = [&](int kv, const f16* kr, const f16* vr, f16* kw, f16* vw) {
        if (kv + 1 < NT) stage(k0b + (kv + 1) * BK, kw, vw);   // lands by tile end

        // ---- QK^T (swapped): each K fragment feeds both q-halves
        f16x sA0, sA1, sB0, sB1;
        #pragma unroll
        for (int r = 0; r < 16; r++) { sA0[r]=0.f; sA1[r]=0.f; sB0[r]=0.f; sB1[r]=0.f; }
        #pragma unroll
        for (int ks = 0; ks < 16; ks++) {
            const int cb = ((ks * 32) | (hi << 4)) ^ rswzK;
            h8_t a0 = *(const h8_t*)((const char*)kr + kbase0 + cb);
            h8_t a1 = *(const h8_t*)((const char*)kr + kbase0 + 16384 + cb);
            sA0 = __builtin_amdgcn_mfma_f32_32x32x16_f16(a0, qfA[ks], sA0, 0, 0, 0);
            sA1 = __builtin_amdgcn_mfma_f32_32x32x16_f16(a1, qfA[ks], sA1, 0, 0, 0);
            sB0 = __builtin_amdgcn_mfma_f32_32x32x16_f16(a0, qfB[ks], sB0, 0, 0, 0);
            sB1 = __builtin_amdgcn_mfma_f32_32x32x16_f16(a1, qfB[ks], sB1, 0, 0, 0);
        }

        softmax(sA0, sA1, oA, mA, lA);
        softmax(sB0, sB1, oB, mB, lB);

        // ---- PV: each V fragment feeds both q-halves
        #pragma unroll
        for (int kb = 0; kb < 2; kb++) {
            const f16x& PA = kb ? sA1 : sA0;
            const f16x& PB = kb ? sB1 : sB0;
            #pragma unroll
            for (int s = 0; s < 2; s++) {
                unsigned int a00 = pk2(PA[8*s+0], PA[8*s+1]);
                unsigned int a01 = pk2(PA[8*s+2], PA[8*s+3]);
                unsigned int a10 = pk2(PA[8*s+4], PA[8*s+5]);
                unsigned int a11 = pk2(PA[8*s+6], PA[8*s+7]);
                asm volatile("v_permlane32_swap_b32 %0, %1" : "+v"(a00), "+v"(a10));
                asm volatile("v_permlane32_swap_b32 %0, %1" : "+v"(a01), "+v"(a11));
                u4_t ua; ua[0]=a00; ua[1]=a01; ua[2]=a10; ua[3]=a11;
                const h8_t apvA = __builtin_bit_cast(h8_t, ua);
                unsigned int b00 = pk2(PB[8*s+0], PB[8*s+1]);
                unsigned int b01 = pk2(PB[8*s+2], PB[8*s+3]);
                unsigned int b10 = pk2(PB[8*s+4], PB[8*s+5]);
                unsigned int b11 = pk2(PB[8*s+6], PB[8*s+7]);
                asm volatile("v_permlane32_swap_b32 %0, %1" : "+v"(b00), "+v"(b10));
                asm volatile("v_permlane32_swap_b32 %0, %1" : "+v"(b01), "+v"(b11));
                u4_t ub; ub[0]=b00; ub[1]=b01; ub[2]=b10; ub[3]=b11;
                const h8_t apvB = __builtin_bit_cast(h8_t, ub);
                const int S = kb * 2 + s;
                const int cb = (vcol0 | (S << 5)) ^ vswz;
                #pragma unroll
                for (int nb = 0; nb < 8; nb++) {
                    h8_t bf = *(const h8_t*)((const char*)vr + nb * 4096 + vbase + cb);
                    oA[nb] = __builtin_amdgcn_mfma_f32_32x32x16_f16(apvA, bf, oA[nb], 0, 0, 0);
                    oB[nb] = __builtin_amdgcn_mfma_f32_32x32x16_f16(apvB, bf, oB[nb], 0, 0, 0);
                }
            }
        }
        __syncthreads();   // next-tile stage complete + all waves done with cur
    };

    for (int kv = 0; kv < NT; kv += 2) {
        tile(kv,     Ks0, Vs0, Ks1, Vs1);
        tile(kv + 1, Ks1, Vs1, Ks0, Vs0);
    }

    // ---- normalized f16 partial O + (m, l) per slice, both halves
    auto writeout = [&](const f16x (&o)[8], float l_run, int qoff) {
        #pragma unroll
        for (int r = 0; r < 16; r++) {
            const int qr = (r & 3) + 8 * (r >> 2) + 4 * hi;
            const float linv = 1.0f / __shfl(l_run, qr);
            const size_t rowoff = ((size_t)sl * NK + qg0 + qoff + qr) * D;
            #pragma unroll
            for (int nb = 0; nb < 8; nb++)
                OPN[rowoff + nb * 32 + q] = (f16)(o[nb][r] * linv);
        }
    };
    writeout(oA, lA, 0);
    writeout(oB, lB, 32);
    if (hi == 0) {
        mpart[(size_t)sl * NK + qg0 + q] = mA;
        lpart[(size_t)sl * NK + qg0 + q] = lA;
        mpart[(size_t)sl * NK + qg0 + 32 + q] = mB;
        lpart[(size_t)sl * NK + qg0 + 32 + q] = lB;
    }
}

// ---------------- MLP1 with fused slice-combine staging.
__global__ __launch_bounds__(256)
void mlp1(const float* __restrict__ guess, const f16* __restrict__ OPN,
          const float* __restrict__ mp, const float* __restrict__ lp,
          const f16* __restrict__ W1C, const float* __restrict__ b1,
          const float* __restrict__ a1, f16* __restrict__ H1)
{
    constexpr int LDA = 40, LDB = 40;
    __shared__ f16 As[64 * LDA];
    __shared__ f16 Bs[256 * LDB];
    __shared__ float cn[64][8];
    const int t = threadIdx.x;
    const int w = t >> 6, l = t & 63, lg = l >> 4, lr = l & 15;
    const int m0 = blockIdx.x * 64;

    if (t < 64) {                         // per-row normalized combine coeffs
        float c[8], M = -3.0e38f;
        #pragma unroll
        for (int s = 0; s < 8; s++) { c[s] = mp[s * 8192 + m0 + t]; M = fmaxf(M, c[s]); }
        float wsum = 0.f;
        #pragma unroll
        for (int s = 0; s < 8; s++) { c[s] = exp2f(c[s] - M) * lp[s * 8192 + m0 + t]; wsum += c[s]; }
        const float inv = 1.0f / wsum;
        #pragma unroll
        for (int s = 0; s < 8; s++) cn[t][s] = c[s] * inv;
    }
    __syncthreads();

    const int arow = t >> 2, ac8 = (t & 3) * 8;
    float cnr[8];
    #pragma unroll
    for (int s = 0; s < 8; s++) cnr[s] = cn[arow][s];

    f4_t acc[4][4] = {};
    for (int kt = 0; kt < 512; kt += 32) {
        {   // A tile 64x32
            h8_t h;
            if (kt < 256) {
                const float* Af = guess + (size_t)(m0 + arow) * 256 + kt + ac8;
                f4_t v0 = *(const f4_t*)Af;
                f4_t v1 = *(const f4_t*)(Af + 4);
                h[0]=(f16)v0[0]; h[1]=(f16)v0[1]; h[2]=(f16)v0[2]; h[3]=(f16)v0[3];
                h[4]=(f16)v1[0]; h[5]=(f16)v1[1]; h[6]=(f16)v1[2]; h[7]=(f16)v1[3];
            } else {
                const int d0 = kt - 256 + ac8;
                f4_t v0 = {0.f,0.f,0.f,0.f}, v1 = {0.f,0.f,0.f,0.f};
                #pragma unroll
                for (int s = 0; s < 8; s++) {
                    h8_t ov = *(const h8_t*)(OPN + ((size_t)s * 8192 + m0 + arow) * 256 + d0);
                    const float c = cnr[s];
                    v0[0] += c * (float)ov[0]; v0[1] += c * (float)ov[1];
                    v0[2] += c * (float)ov[2]; v0[3] += c * (float)ov[3];
                    v1[0] += c * (float)ov[4]; v1[1] += c * (float)ov[5];
                    v1[2] += c * (float)ov[6]; v1[3] += c * (float)ov[7];
                }
                h[0]=(f16)v0[0]; h[1]=(f16)v0[1]; h[2]=(f16)v0[2]; h[3]=(f16)v0[3];
                h[4]=(f16)v1[0]; h[5]=(f16)v1[1]; h[6]=(f16)v1[2]; h[7]=(f16)v1[3];
            }
            *(h8_t*)(&As[arow * LDA + ac8]) = h;
        }
        #pragma unroll
        for (int i = 0; i < 4; i++) {      // B tile 256x32
            int s0 = t + i * 256;
            int row = s0 >> 2, c8 = (s0 & 3) * 8;
            *(u4_t*)(&Bs[row * LDB + c8]) =
                *(const u4_t*)(W1C + (size_t)row * 512 + kt + c8);
        }
        __syncthreads();
        h8_t af[4], bf[4];
        #pragma unroll
        for (int mf = 0; mf < 4; mf++)
            af[mf] = *(const h8_t*)(&As[(mf * 16 + lr) * LDA + lg * 8]);
        #pragma unroll
        for (int nf = 0; nf < 4; nf++)
            bf[nf] = *(const h8_t*)(&Bs[(w * 64 + nf * 16 + lr) * LDB + lg * 8]);
        #pragma unroll
        for (int mf = 0; mf < 4; mf++)
            #pragma unroll
            for (int nf = 0; nf < 4; nf++)
                acc[mf][nf] = __builtin_amdgcn_mfma_f32_16x16x32_f16(
                    af[mf], bf[nf], acc[mf][nf], 0, 0, 0);
        __syncthreads();
    }

    const float av = *a1;
    #pragma unroll
    for (int mf = 0; mf < 4; mf++)
        #pragma unroll
        for (int nf = 0; nf < 4; nf++)
            #pragma unroll
            for (int r = 0; r < 4; r++) {
                int row = m0 + mf * 16 + lg * 4 + r;
                int col = w * 64 + nf * 16 + lr;
                float v = acc[mf][nf][r] + b1[col];
                v = v > 0.f ? v : av * v;
                H1[(size_t)row * 256 + col] = (f16)v;
            }
}

// ---------------- MLP2 + final W3 dot. M=8192, N=128, K=256. BM=64 BN=128.
__global__ __launch_bounds__(256)
void mlp2_final(const f16* __restrict__ H1, const f16* __restrict__ W216,
                const float* __restrict__ b2, const float* __restrict__ a2,
                const float* __restrict__ W3, const float* __restrict__ b3,
                float* __restrict__ out)
{
    constexpr int LDA = 40, LDB = 40;
    __shared__ f16 As[64 * LDA];
    __shared__ f16 Bs[128 * LDB];
    __shared__ float part[64][68];
    const int t = threadIdx.x;
    const int w = t >> 6, l = t & 63, lg = l >> 4, lr = l & 15;
    const int m0 = blockIdx.x * 64;
    f4_t acc[4][2] = {};

    for (int kt = 0; kt < 256; kt += 32) {
        const int row = t >> 2, c8 = (t & 3) * 8;
        *(u4_t*)(&As[row * LDA + c8]) =
            *(const u4_t*)(H1 + (size_t)(m0 + row) * 256 + kt + c8);
        *(u4_t*)(&Bs[row * LDB + c8]) =
            *(const u4_t*)(W216 + (size_t)row * 256 + kt + c8);
        *(u4_t*)(&Bs[(row + 64) * LDB + c8]) =
            *(const u4_t*)(W216 + (size_t)(row + 64) * 256 + kt + c8);
        __syncthreads();
        h8_t af[4], bf[2];
        #pragma unroll
        for (int mf = 0; mf < 4; mf++)
            af[mf] = *(const h8_t*)(&As[(mf * 16 + lr) * LDA + lg * 8]);
        #pragma unroll
        for (int nf = 0; nf < 2; nf++)
            bf[nf] = *(const h8_t*)(&Bs[(w * 32 + nf * 16 + lr) * LDB + lg * 8]);
        #pragma unroll
        for (int mf = 0; mf < 4; mf++)
            #pragma unroll
            for (int nf = 0; nf < 2; nf++)
                acc[mf][nf] = __builtin_amdgcn_mfma_f32_16x16x32_f16(
                    af[mf], bf[nf], acc[mf][nf], 0, 0, 0);
        __syncthreads();
    }

    const float av = *a2;
    #pragma unroll
    for (int mf = 0; mf < 4; mf++)
        #pragma unroll
        for (int r = 0; r < 4; r++) {
            float p = 0.f;
            #pragma unroll
            for (int nf = 0; nf < 2; nf++) {
                const int col = w * 32 + nf * 16 + lr;
                float v = acc[mf][nf][r] + b2[col];
                v = v > 0.f ? v : av * v;
                p += v * W3[col];
            }
            part[mf * 16 + lg * 4 + r][w * 16 + lr] = p;
        }
    __syncthreads();
    const int row = t >> 2, q4 = t & 3;
    float s2 = 0.f;
    #pragma unroll
    for (int j = 0; j < 16; j++) s2 += part[row][q4 * 16 + j];
    s2 += __shfl_xor(s2, 1);
    s2 += __shfl_xor(s2, 2);
    if (q4 == 0) out[m0 + row] = s2 + b3[0];
}

// ============================================================================
extern "C" void kernel_launch(void* const* d_in, const int* in_sizes, int n_in,
                              void* d_out, int out_size, void* d_ws, size_t ws_size,
                              hipStream_t stream)
{
    const float* anchor = (const float*)d_in[0];
    const float* guess  = (const float*)d_in[1];
    const float* Wa = (const float*)d_in[2];
    const float* ba = (const float*)d_in[3];
    const float* Wg = (const float*)d_in[4];
    const float* bg = (const float*)d_in[5];
    const float* W1 = (const float*)d_in[6];
    const float* b1 = (const float*)d_in[7];
    const float* a1 = (const float*)d_in[8];
    const float* W2 = (const float*)d_in[9];
    const float* b2 = (const float*)d_in[10];
    const float* a2 = (const float*)d_in[11];
    const float* W3 = (const float*)d_in[12];
    const float* b3 = (const float*)d_in[13];
    float* out = (float*)d_out;
    char* ws = (char*)d_ws;

    const size_t MB = 1u << 20;
    f16* GE16 = (f16*)(ws + 0 * MB);                    // Q (x log2e)   4 MB
    f16* AC16 = (f16*)(ws + 4 * MB);                    // K             4 MB
    f16* VT16 = (f16*)(ws + 8 * MB);                    // V^T           4 MB
    f16* OPN  = (f16*)(ws + 12 * MB);                   // 8x[8192][256] 32 MB
    f16* WA16 = (f16*)(ws + 44 * MB);                   // 128 KB
    f16* WG16 = (f16*)(ws + 44 * MB + 128 * 1024);      // 128 KB
    f16* W1C  = (f16*)(ws + 44 * MB + 256 * 1024);      // 256 KB
    f16* W216 = (f16*)(ws + 44 * MB + 512 * 1024);      // 64 KB
    float* MP = (float*)(ws + 45 * MB);                 // 256 KB
    float* LP = (float*)(ws + 45 * MB + 256 * 1024);    // 256 KB
    f16* H1   = (f16*)(ws + 0 * MB);                    // 4 MB (over GE16, post-flash)

    prep<<<288, 256, 0, stream>>>(Wa, Wg, W1, W2, WA16, WG16, W1C, W216);

    proj_pair<<<dim3(128, 2, 2), 256, 0, stream>>>(
        guess, anchor, WG16, WA16, bg, ba, GE16, AC16, VT16);

    flash_attn<<<256, 256, 0, stream>>>(GE16, AC16, VT16, OPN, MP, LP);

    mlp1<<<128, 256, 0, stream>>>(guess, OPN, MP, LP, W1C, b1, a1, H1);

    mlp2_final<<<128, 256, 0, stream>>>(H1, W216, b2, a2, W3, b3, out);
}

// Round 13
// 392.675 us; speedup vs baseline: 1.1640x; 1.1640x over previous
//
#include <hip/hip_runtime.h>

// Round 13: r7 pipeline with ONE flash change: V direct-from-global (r8-verified
// PV pattern) + freed LDS used for K double-buffer -> ONE barrier per tile.
// Register envelope = r7 (no spill); NSL=8; everything else r7-verbatim.

typedef _Float16 f16;
typedef _Float16 h8_t  __attribute__((ext_vector_type(8)));
typedef _Float16 h4_t  __attribute__((ext_vector_type(4)));
typedef float    f4_t  __attribute__((ext_vector_type(4)));
typedef float    f16x  __attribute__((ext_vector_type(16)));
typedef unsigned int u4_t  __attribute__((ext_vector_type(4)));

#define LOG2E 1.4426950408889634f

__device__ __forceinline__ void llds16(const f16* g, f16* s) {
    __builtin_amdgcn_global_load_lds(
        (const __attribute__((address_space(1))) void*)g,
        (__attribute__((address_space(3))) void*)s, 16, 0, 0);
}
__device__ __forceinline__ unsigned int pk2(float a, float b) {
    auto h = __builtin_amdgcn_cvt_pkrtz(a, b);
    return __builtin_bit_cast(unsigned int, h);
}

// ---------------- prep: weights f32->f16 (+W1 combine). 288 blocks.
__global__ __launch_bounds__(256)
void prep(const float* __restrict__ Wa, const float* __restrict__ Wg,
          const float* __restrict__ W1, const float* __restrict__ W2,
          f16* __restrict__ oa, f16* __restrict__ og,
          f16* __restrict__ o1c, f16* __restrict__ o2)
{
    int i = blockIdx.x * 256 + threadIdx.x;   // quad index; total 73728
    if (i < 40960) {
        const float* s; f16* d; int off;
        if (i < 16384)      { s = Wa; d = oa; off = i; }
        else if (i < 32768) { s = Wg; d = og; off = i - 16384; }
        else                { s = W2; d = o2; off = i - 32768; }
        f4_t v = ((const f4_t*)s)[off];
        h4_t h;
        h[0]=(f16)v[0]; h[1]=(f16)v[1]; h[2]=(f16)v[2]; h[3]=(f16)v[3];
        ((h4_t*)d)[off] = h;
    } else {
        int off = i - 40960;                  // W1comb [256][512]
        int j = off >> 7, c0 = (off & 127) * 4;
        const float* r = W1 + (size_t)j * 768;
        f4_t v0, v1;
        if (c0 < 256) { v0 = *(const f4_t*)(r + c0); v1 = *(const f4_t*)(r + 512 + c0); }
        else          { v0 = *(const f4_t*)(r + c0); v1 = *(const f4_t*)(r + 256 + c0); }
        h4_t h;
        #pragma unroll
        for (int e = 0; e < 4; e++)
            h[e] = (f16)(c0 < 256 ? v0[e] + v1[e] : v0[e] - v1[e]);
        ((h4_t*)o1c)[off] = h;
    }
}

// ---------------- both projections in one launch; z=1 (anchor) bn==0 emits VT
__global__ __launch_bounds__(256)
void proj_pair(const float* __restrict__ guess, const float* __restrict__ anchor,
               const f16* __restrict__ WG, const f16* __restrict__ WA,
               const float* __restrict__ bg, const float* __restrict__ ba,
               f16* __restrict__ GE, f16* __restrict__ AC,
               f16* __restrict__ vt)
{
    constexpr int BK = 32, LDA = 40, LDB = 40;
    __shared__ f16 As[64 * LDA];
    __shared__ f16 Bs[128 * LDB];
    const int t = threadIdx.x;
    const int w = t >> 6, l = t & 63, lg = l >> 4, lr = l & 15;
    const int bm = blockIdx.x, bn = blockIdx.y, z = blockIdx.z;
    const float* A   = z ? anchor : guess;
    const f16*   B   = z ? WA : WG;
    const float* bias= z ? ba : bg;
    const float scale= z ? 1.0f : LOG2E;
    f16* C = z ? AC : GE;
    f4_t acc[4][2] = {};

    for (int kt = 0; kt < 256; kt += BK) {
        {   // A tile 64x32, f32 -> f16
            int row = t >> 2, c8 = (t & 3) * 8;
            const float* Af = A + (size_t)(bm * 64 + row) * 256 + kt + c8;
            f4_t v0 = *(const f4_t*)Af;
            f4_t v1 = *(const f4_t*)(Af + 4);
            h8_t h;
            h[0]=(f16)v0[0]; h[1]=(f16)v0[1]; h[2]=(f16)v0[2]; h[3]=(f16)v0[3];
            h[4]=(f16)v1[0]; h[5]=(f16)v1[1]; h[6]=(f16)v1[2]; h[7]=(f16)v1[3];
            *(h8_t*)(&As[row * LDA + c8]) = h;
        }
        {   // B tile 128x32
            int s0 = t, row = s0 >> 2, c8 = (s0 & 3) * 8;
            *(u4_t*)(&Bs[row * LDB + c8]) =
                *(const u4_t*)(B + (size_t)(bn * 128 + row) * 256 + kt + c8);
            int s1 = t + 256; row = s1 >> 2; c8 = (s1 & 3) * 8;
            *(u4_t*)(&Bs[row * LDB + c8]) =
                *(const u4_t*)(B + (size_t)(bn * 128 + row) * 256 + kt + c8);
        }
        __syncthreads();
        h8_t af[4], bf[2];
        #pragma unroll
        for (int mf = 0; mf < 4; mf++)
            af[mf] = *(const h8_t*)(&As[(mf * 16 + lr) * LDA + lg * 8]);
        #pragma unroll
        for (int nf = 0; nf < 2; nf++)
            bf[nf] = *(const h8_t*)(&Bs[(w * 32 + nf * 16 + lr) * LDB + lg * 8]);
        #pragma unroll
        for (int mf = 0; mf < 4; mf++)
            #pragma unroll
            for (int nf = 0; nf < 2; nf++)
                acc[mf][nf] = __builtin_amdgcn_mfma_f32_16x16x32_f16(
                    af[mf], bf[nf], acc[mf][nf], 0, 0, 0);
        // fused anchor^T emit (z==1, bn==0 only; As holds anchor f16 tile)
        if (z == 1 && bn == 0) {
            const int c = t >> 3, r0 = (t & 7) * 8;
            h8_t h;
            #pragma unroll
            for (int j = 0; j < 8; j++) h[j] = As[(r0 + j) * LDA + c];
            *(h8_t*)(vt + (size_t)(kt + c) * 8192 + bm * 64 + r0) = h;
        }
        __syncthreads();
    }

    #pragma unroll
    for (int mf = 0; mf < 4; mf++)
        #pragma unroll
        for (int nf = 0; nf < 2; nf++)
            #pragma unroll
            for (int r = 0; r < 4; r++) {
                int row = bm * 64 + mf * 16 + lg * 4 + r;
                int col = bn * 128 + w * 32 + nf * 16 + lr;
                C[(size_t)row * 256 + col] = (f16)((acc[mf][nf][r] + bias[col]) * scale);
            }
}

// ------------------------------------------------------------- flash attention
// K double-buffered in LDS (2x32KB, swizzled, global_load_lds, stage at tile
// top); V fragments direct from global (r8-verified pattern, L1-broadcast).
// ONE barrier per tile. 4 waves x 32q = 128 q/block; grid 512 (sl=bid&7).
__global__ __launch_bounds__(256, 2)
void flash_attn(const f16* __restrict__ Q, const f16* __restrict__ Kc,
                const f16* __restrict__ Vt, f16* __restrict__ OPN,
                float* __restrict__ mpart, float* __restrict__ lpart)
{
    constexpr int D = 256, BK = 64, NK = 8192, SL = 1024, NT = SL / BK;
    __shared__ f16 Ks0[BK * D];   // 32 KB
    __shared__ f16 Ks1[BK * D];   // 32 KB
    const int t = threadIdx.x, w = t >> 6, l = t & 63;
    const int q = l & 31, hi = l >> 5;
    const int sl = blockIdx.x & 7, qb = blockIdx.x >> 3;
    const int k0b = sl * SL;
    const int qg0 = qb * 128 + w * 32;

    h8_t qf[16];
    {
        const f16* qr = Q + (size_t)(qg0 + q) * D + hi * 8;
        #pragma unroll
        for (int ks = 0; ks < 16; ks++) qf[ks] = *(const h8_t*)(qr + ks * 16);
    }

    const int sK0 = ((t & 31) ^ (t >> 5)) << 3;
    auto stageK = [&](int k0, f16* kd) {
        #pragma unroll
        for (int i = 0; i < 8; i++) {
            const f16* g = Kc + (size_t)(k0 + i * 8 + (t >> 5)) * D + (sK0 ^ ((i & 1) << 6));
            llds16(g, kd + i * 2048 + w * 512);
        }
    };

    // V direct-from-global lane base (r8-verified fragment pattern)
    const f16* vrow = Vt + (size_t)q * NK + k0b + hi * 8;

    stageK(k0b, Ks0);
    __syncthreads();

    f16x o[8] = {};
    float m_run = -1e30f, l_run = 0.f;
    const int rswzK = (q & 15) << 4;
    const int kbase0 = q * 512;

    auto tile = [&](int kv, const f16* kr, f16* kw) {
        if (kv + 1 < NT) stageK(k0b + (kv + 1) * BK, kw);  // full-tile window

        // ---- QK^T (swapped): sa[m=key][n=q], K from swizzled LDS
        f16x sa0, sa1;
        #pragma unroll
        for (int r = 0; r < 16; r++) { sa0[r] = 0.f; sa1[r] = 0.f; }
        #pragma unroll
        for (int ks = 0; ks < 16; ks++) {
            const int cb = ((ks * 32) | (hi << 4)) ^ rswzK;
            h8_t a0 = *(const h8_t*)((const char*)kr + kbase0 + cb);
            h8_t a1 = *(const h8_t*)((const char*)kr + kbase0 + 16384 + cb);
            sa0 = __builtin_amdgcn_mfma_f32_32x32x16_f16(a0, qf[ks], sa0, 0, 0, 0);
            sa1 = __builtin_amdgcn_mfma_f32_32x32x16_f16(a1, qf[ks], sa1, 0, 0, 0);
        }

        // ---- online softmax (log2 domain), defer-max
        float mt = sa0[0];
        #pragma unroll
        for (int r = 1; r < 16; r++) mt = fmaxf(mt, sa0[r]);
        #pragma unroll
        for (int r = 0; r < 16; r++) mt = fmaxf(mt, sa1[r]);
        mt = fmaxf(mt, __shfl_xor(mt, 32));
        if (!__all(mt <= m_run + 8.0f)) {
            const float mnew = fmaxf(m_run, mt);
            const float corr = exp2f(m_run - mnew);
            #pragma unroll
            for (int r = 0; r < 16; r++) {
                const float c = __shfl(corr, (r & 3) + 8 * (r >> 2) + 4 * hi);
                #pragma unroll
                for (int nb = 0; nb < 8; nb++) o[nb][r] *= c;
            }
            l_run *= corr;
            m_run = mnew;
        }
        float rs = 0.f;
        #pragma unroll
        for (int r = 0; r < 16; r++) { sa0[r] = exp2f(sa0[r] - m_run); rs += sa0[r]; }
        #pragma unroll
        for (int r = 0; r < 16; r++) { sa1[r] = exp2f(sa1[r] - m_run); rs += sa1[r]; }
        rs += __shfl_xor(rs, 32);
        l_run += rs;

        // ---- PV: A = packed P, B = V fragments direct from global (L1/L2)
        const f16* vp = vrow + kv * BK;
        #pragma unroll
        for (int kb = 0; kb < 2; kb++) {
            const f16x& P = kb ? sa1 : sa0;
            #pragma unroll
            for (int s = 0; s < 2; s++) {
                unsigned int w00 = pk2(P[8*s+0], P[8*s+1]);
                unsigned int w01 = pk2(P[8*s+2], P[8*s+3]);
                unsigned int w10 = pk2(P[8*s+4], P[8*s+5]);
                unsigned int w11 = pk2(P[8*s+6], P[8*s+7]);
                asm volatile("v_permlane32_swap_b32 %0, %1" : "+v"(w00), "+v"(w10));
                asm volatile("v_permlane32_swap_b32 %0, %1" : "+v"(w01), "+v"(w11));
                u4_t up; up[0] = w00; up[1] = w01; up[2] = w10; up[3] = w11;
                const h8_t apv = __builtin_bit_cast(h8_t, up);
                const int S = kb * 2 + s;
                #pragma unroll
                for (int nb = 0; nb < 8; nb++) {
                    h8_t bf = *(const h8_t*)(vp + (size_t)nb * (32 * NK) + S * 16);
                    o[nb] = __builtin_amdgcn_mfma_f32_32x32x16_f16(apv, bf, o[nb], 0, 0, 0);
                }
            }
        }

        __syncthreads();   // drains own stage loads (full-tile window) + sync
    };

    for (int kv = 0; kv < NT; kv += 2) {
        tile(kv,     Ks0, Ks1);
        tile(kv + 1, Ks1, Ks0);
    }

    #pragma unroll
    for (int r = 0; r < 16; r++) {
        const int qr = (r & 3) + 8 * (r >> 2) + 4 * hi;
        const float linv = 1.0f / __shfl(l_run, qr);
        const size_t rowoff = ((size_t)sl * NK + qg0 + qr) * D;
        #pragma unroll
        for (int nb = 0; nb < 8; nb++)
            OPN[rowoff + nb * 32 + q] = (f16)(o[nb][r] * linv);
    }
    if (hi == 0) {
        mpart[(size_t)sl * NK + qg0 + q] = m_run;
        lpart[(size_t)sl * NK + qg0 + q] = l_run;
    }
}

// ---------------- MLP1 with fused slice-combine staging.
__global__ __launch_bounds__(256)
void mlp1(const float* __restrict__ guess, const f16* __restrict__ OPN,
          const float* __restrict__ mp, const float* __restrict__ lp,
          const f16* __restrict__ W1C, const float* __restrict__ b1,
          const float* __restrict__ a1, f16* __restrict__ H1)
{
    constexpr int LDA = 40, LDB = 40;
    __shared__ f16 As[64 * LDA];
    __shared__ f16 Bs[256 * LDB];
    __shared__ float cn[64][8];
    const int t = threadIdx.x;
    const int w = t >> 6, l = t & 63, lg = l >> 4, lr = l & 15;
    const int m0 = blockIdx.x * 64;

    if (t < 64) {                         // per-row normalized combine coeffs
        float c[8], M = -3.0e38f;
        #pragma unroll
        for (int s = 0; s < 8; s++) { c[s] = mp[s * 8192 + m0 + t]; M = fmaxf(M, c[s]); }
        float wsum = 0.f;
        #pragma unroll
        for (int s = 0; s < 8; s++) { c[s] = exp2f(c[s] - M) * lp[s * 8192 + m0 + t]; wsum += c[s]; }
        const float inv = 1.0f / wsum;
        #pragma unroll
        for (int s = 0; s < 8; s++) cn[t][s] = c[s] * inv;
    }
    __syncthreads();

    const int arow = t >> 2, ac8 = (t & 3) * 8;
    float cnr[8];
    #pragma unroll
    for (int s = 0; s < 8; s++) cnr[s] = cn[arow][s];

    f4_t acc[4][4] = {};
    for (int kt = 0; kt < 512; kt += 32) {
        {   // A tile 64x32
            h8_t h;
            if (kt < 256) {
                const float* Af = guess + (size_t)(m0 + arow) * 256 + kt + ac8;
                f4_t v0 = *(const f4_t*)Af;
                f4_t v1 = *(const f4_t*)(Af + 4);
                h[0]=(f16)v0[0]; h[1]=(f16)v0[1]; h[2]=(f16)v0[2]; h[3]=(f16)v0[3];
                h[4]=(f16)v1[0]; h[5]=(f16)v1[1]; h[6]=(f16)v1[2]; h[7]=(f16)v1[3];
            } else {
                const int d0 = kt - 256 + ac8;
                f4_t v0 = {0.f,0.f,0.f,0.f}, v1 = {0.f,0.f,0.f,0.f};
                #pragma unroll
                for (int s = 0; s < 8; s++) {
                    h8_t ov = *(const h8_t*)(OPN + ((size_t)s * 8192 + m0 + arow) * 256 + d0);
                    const float c = cnr[s];
                    v0[0] += c * (float)ov[0]; v0[1] += c * (float)ov[1];
                    v0[2] += c * (float)ov[2]; v0[3] += c * (float)ov[3];
                    v1[0] += c * (float)ov[4]; v1[1] += c * (float)ov[5];
                    v1[2] += c * (float)ov[6]; v1[3] += c * (float)ov[7];
                }
                h[0]=(f16)v0[0]; h[1]=(f16)v0[1]; h[2]=(f16)v0[2]; h[3]=(f16)v0[3];
                h[4]=(f16)v1[0]; h[5]=(f16)v1[1]; h[6]=(f16)v1[2]; h[7]=(f16)v1[3];
            }
            *(h8_t*)(&As[arow * LDA + ac8]) = h;
        }
        #pragma unroll
        for (int i = 0; i < 4; i++) {      // B tile 256x32
            int s0 = t + i * 256;
            int row = s0 >> 2, c8 = (s0 & 3) * 8;
            *(u4_t*)(&Bs[row * LDB + c8]) =
                *(const u4_t*)(W1C + (size_t)row * 512 + kt + c8);
        }
        __syncthreads();
        h8_t af[4], bf[4];
        #pragma unroll
        for (int mf = 0; mf < 4; mf++)
            af[mf] = *(const h8_t*)(&As[(mf * 16 + lr) * LDA + lg * 8]);
        #pragma unroll
        for (int nf = 0; nf < 4; nf++)
            bf[nf] = *(const h8_t*)(&Bs[(w * 64 + nf * 16 + lr) * LDB + lg * 8]);
        #pragma unroll
        for (int mf = 0; mf < 4; mf++)
            #pragma unroll
            for (int nf = 0; nf < 4; nf++)
                acc[mf][nf] = __builtin_amdgcn_mfma_f32_16x16x32_f16(
                    af[mf], bf[nf], acc[mf][nf], 0, 0, 0);
        __syncthreads();
    }

    const float av = *a1;
    #pragma unroll
    for (int mf = 0; mf < 4; mf++)
        #pragma unroll
        for (int nf = 0; nf < 4; nf++)
            #pragma unroll
            for (int r = 0; r < 4; r++) {
                int row = m0 + mf * 16 + lg * 4 + r;
                int col = w * 64 + nf * 16 + lr;
                float v = acc[mf][nf][r] + b1[col];
                v = v > 0.f ? v : av * v;
                H1[(size_t)row * 256 + col] = (f16)v;
            }
}

// ---------------- MLP2 + final W3 dot. M=8192, N=128, K=256. BM=64 BN=128.
__global__ __launch_bounds__(256)
void mlp2_final(const f16* __restrict__ H1, const f16* __restrict__ W216,
                const float* __restrict__ b2, const float* __restrict__ a2,
                const float* __restrict__ W3, const float* __restrict__ b3,
                float* __restrict__ out)
{
    constexpr int LDA = 40, LDB = 40;
    __shared__ f16 As[64 * LDA];
    __shared__ f16 Bs[128 * LDB];
    __shared__ float part[64][68];
    const int t = threadIdx.x;
    const int w = t >> 6, l = t & 63, lg = l >> 4, lr = l & 15;
    const int m0 = blockIdx.x * 64;
    f4_t acc[4][2] = {};

    for (int kt = 0; kt < 256; kt += 32) {
        const int row = t >> 2, c8 = (t & 3) * 8;
        *(u4_t*)(&As[row * LDA + c8]) =
            *(const u4_t*)(H1 + (size_t)(m0 + row) * 256 + kt + c8);
        *(u4_t*)(&Bs[row * LDB + c8]) =
            *(const u4_t*)(W216 + (size_t)row * 256 + kt + c8);
        *(u4_t*)(&Bs[(row + 64) * LDB + c8]) =
            *(const u4_t*)(W216 + (size_t)(row + 64) * 256 + kt + c8);
        __syncthreads();
        h8_t af[4], bf[2];
        #pragma unroll
        for (int mf = 0; mf < 4; mf++)
            af[mf] = *(const h8_t*)(&As[(mf * 16 + lr) * LDA + lg * 8]);
        #pragma unroll
        for (int nf = 0; nf < 2; nf++)
            bf[nf] = *(const h8_t*)(&Bs[(w * 32 + nf * 16 + lr) * LDB + lg * 8]);
        #pragma unroll
        for (int mf = 0; mf < 4; mf++)
            #pragma unroll
            for (int nf = 0; nf < 2; nf++)
                acc[mf][nf] = __builtin_amdgcn_mfma_f32_16x16x32_f16(
                    af[mf], bf[nf], acc[mf][nf], 0, 0, 0);
        __syncthreads();
    }

    const float av = *a2;
    #pragma unroll
    for (int mf = 0; mf < 4; mf++)
        #pragma unroll
        for (int r = 0; r < 4; r++) {
            float p = 0.f;
            #pragma unroll
            for (int nf = 0; nf < 2; nf++) {
                const int col = w * 32 + nf * 16 + lr;
                float v = acc[mf][nf][r] + b2[col];
                v = v > 0.f ? v : av * v;
                p += v * W3[col];
            }
            part[mf * 16 + lg * 4 + r][w * 16 + lr] = p;
        }
    __syncthreads();
    const int row = t >> 2, q4 = t & 3;
    float s2 = 0.f;
    #pragma unroll
    for (int j = 0; j < 16; j++) s2 += part[row][q4 * 16 + j];
    s2 += __shfl_xor(s2, 1);
    s2 += __shfl_xor(s2, 2);
    if (q4 == 0) out[m0 + row] = s2 + b3[0];
}

// ============================================================================
extern "C" void kernel_launch(void* const* d_in, const int* in_sizes, int n_in,
                              void* d_out, int out_size, void* d_ws, size_t ws_size,
                              hipStream_t stream)
{
    const float* anchor = (const float*)d_in[0];
    const float* guess  = (const float*)d_in[1];
    const float* Wa = (const float*)d_in[2];
    const float* ba = (const float*)d_in[3];
    const float* Wg = (const float*)d_in[4];
    const float* bg = (const float*)d_in[5];
    const float* W1 = (const float*)d_in[6];
    const float* b1 = (const float*)d_in[7];
    const float* a1 = (const float*)d_in[8];
    const float* W2 = (const float*)d_in[9];
    const float* b2 = (const float*)d_in[10];
    const float* a2 = (const float*)d_in[11];
    const float* W3 = (const float*)d_in[12];
    const float* b3 = (const float*)d_in[13];
    float* out = (float*)d_out;
    char* ws = (char*)d_ws;

    const size_t MB = 1u << 20;
    f16* GE16 = (f16*)(ws + 0 * MB);                    // Q (x log2e)   4 MB
    f16* AC16 = (f16*)(ws + 4 * MB);                    // K             4 MB
    f16* VT16 = (f16*)(ws + 8 * MB);                    // V^T           4 MB
    f16* OPN  = (f16*)(ws + 12 * MB);                   // 8x[8192][256] 32 MB
    f16* WA16 = (f16*)(ws + 44 * MB);                   // 128 KB
    f16* WG16 = (f16*)(ws + 44 * MB + 128 * 1024);      // 128 KB
    f16* W1C  = (f16*)(ws + 44 * MB + 256 * 1024);      // 256 KB
    f16* W216 = (f16*)(ws + 44 * MB + 512 * 1024);      // 64 KB
    float* MP = (float*)(ws + 45 * MB);                 // 256 KB
    float* LP = (float*)(ws + 45 * MB + 256 * 1024);    // 256 KB
    f16* H1   = (f16*)(ws + 0 * MB);                    // 4 MB (over GE16, post-flash)

    prep<<<288, 256, 0, stream>>>(Wa, Wg, W1, W2, WA16, WG16, W1C, W216);

    proj_pair<<<dim3(128, 2, 2), 256, 0, stream>>>(
        guess, anchor, WG16, WA16, bg, ba, GE16, AC16, VT16);

    flash_attn<<<512, 256, 0, stream>>>(GE16, AC16, VT16, OPN, MP, LP);

    mlp1<<<128, 256, 0, stream>>>(guess, OPN, MP, LP, W1C, b1, a1, H1);

    mlp2_final<<<128, 256, 0, stream>>>(H1, W216, b2, a2, W3, b3, out);
}

// Round 14
// 161.219 us; speedup vs baseline: 2.8351x; 2.4357x over previous
//
#include <hip/hip_runtime.h>

// Round 14: revert to the round-7 kernel verbatim — the measured optimum
// (161.2 µs). Rounds 8-13 established that every flash variation either
// spills past the 128-VGPR/(256,2) cap (setprio r6, 1-barrier dbuf r13,
// 64q/wave r11, (256,4) r12), is neutral (stagger r9, counted-vmcnt r10),
// or regresses (un-staged V/K r8). This structure is the fixed point.

typedef _Float16 f16;
typedef _Float16 h8_t  __attribute__((ext_vector_type(8)));
typedef _Float16 h4_t  __attribute__((ext_vector_type(4)));
typedef float    f4_t  __attribute__((ext_vector_type(4)));
typedef float    f16x  __attribute__((ext_vector_type(16)));
typedef unsigned int u4_t  __attribute__((ext_vector_type(4)));

#define LOG2E 1.4426950408889634f

__device__ __forceinline__ void llds16(const f16* g, f16* s) {
    __builtin_amdgcn_global_load_lds(
        (const __attribute__((address_space(1))) void*)g,
        (__attribute__((address_space(3))) void*)s, 16, 0, 0);
}
__device__ __forceinline__ unsigned int pk2(float a, float b) {
    auto h = __builtin_amdgcn_cvt_pkrtz(a, b);
    return __builtin_bit_cast(unsigned int, h);
}

// ---------------- prep: weights f32->f16 (+W1 combine). 288 blocks.
__global__ __launch_bounds__(256)
void prep(const float* __restrict__ Wa, const float* __restrict__ Wg,
          const float* __restrict__ W1, const float* __restrict__ W2,
          f16* __restrict__ oa, f16* __restrict__ og,
          f16* __restrict__ o1c, f16* __restrict__ o2)
{
    int i = blockIdx.x * 256 + threadIdx.x;   // quad index; total 73728
    if (i < 40960) {
        const float* s; f16* d; int off;
        if (i < 16384)      { s = Wa; d = oa; off = i; }
        else if (i < 32768) { s = Wg; d = og; off = i - 16384; }
        else                { s = W2; d = o2; off = i - 32768; }
        f4_t v = ((const f4_t*)s)[off];
        h4_t h;
        h[0]=(f16)v[0]; h[1]=(f16)v[1]; h[2]=(f16)v[2]; h[3]=(f16)v[3];
        ((h4_t*)d)[off] = h;
    } else {
        int off = i - 40960;                  // W1comb [256][512]
        int j = off >> 7, c0 = (off & 127) * 4;
        const float* r = W1 + (size_t)j * 768;
        f4_t v0, v1;
        if (c0 < 256) { v0 = *(const f4_t*)(r + c0); v1 = *(const f4_t*)(r + 512 + c0); }
        else          { v0 = *(const f4_t*)(r + c0); v1 = *(const f4_t*)(r + 256 + c0); }
        h4_t h;
        #pragma unroll
        for (int e = 0; e < 4; e++)
            h[e] = (f16)(c0 < 256 ? v0[e] + v1[e] : v0[e] - v1[e]);
        ((h4_t*)o1c)[off] = h;
    }
}

// ---------------- both projections in one launch; z=1 (anchor) bn==0 emits VT
__global__ __launch_bounds__(256)
void proj_pair(const float* __restrict__ guess, const float* __restrict__ anchor,
               const f16* __restrict__ WG, const f16* __restrict__ WA,
               const float* __restrict__ bg, const float* __restrict__ ba,
               f16* __restrict__ GE, f16* __restrict__ AC,
               f16* __restrict__ vt)
{
    constexpr int BK = 32, LDA = 40, LDB = 40;
    __shared__ f16 As[64 * LDA];
    __shared__ f16 Bs[128 * LDB];
    const int t = threadIdx.x;
    const int w = t >> 6, l = t & 63, lg = l >> 4, lr = l & 15;
    const int bm = blockIdx.x, bn = blockIdx.y, z = blockIdx.z;
    const float* A   = z ? anchor : guess;
    const f16*   B   = z ? WA : WG;
    const float* bias= z ? ba : bg;
    const float scale= z ? 1.0f : LOG2E;
    f16* C = z ? AC : GE;
    f4_t acc[4][2] = {};

    for (int kt = 0; kt < 256; kt += BK) {
        {   // A tile 64x32, f32 -> f16
            int row = t >> 2, c8 = (t & 3) * 8;
            const float* Af = A + (size_t)(bm * 64 + row) * 256 + kt + c8;
            f4_t v0 = *(const f4_t*)Af;
            f4_t v1 = *(const f4_t*)(Af + 4);
            h8_t h;
            h[0]=(f16)v0[0]; h[1]=(f16)v0[1]; h[2]=(f16)v0[2]; h[3]=(f16)v0[3];
            h[4]=(f16)v1[0]; h[5]=(f16)v1[1]; h[6]=(f16)v1[2]; h[7]=(f16)v1[3];
            *(h8_t*)(&As[row * LDA + c8]) = h;
        }
        {   // B tile 128x32
            int s0 = t, row = s0 >> 2, c8 = (s0 & 3) * 8;
            *(u4_t*)(&Bs[row * LDB + c8]) =
                *(const u4_t*)(B + (size_t)(bn * 128 + row) * 256 + kt + c8);
            int s1 = t + 256; row = s1 >> 2; c8 = (s1 & 3) * 8;
            *(u4_t*)(&Bs[row * LDB + c8]) =
                *(const u4_t*)(B + (size_t)(bn * 128 + row) * 256 + kt + c8);
        }
        __syncthreads();
        h8_t af[4], bf[2];
        #pragma unroll
        for (int mf = 0; mf < 4; mf++)
            af[mf] = *(const h8_t*)(&As[(mf * 16 + lr) * LDA + lg * 8]);
        #pragma unroll
        for (int nf = 0; nf < 2; nf++)
            bf[nf] = *(const h8_t*)(&Bs[(w * 32 + nf * 16 + lr) * LDB + lg * 8]);
        #pragma unroll
        for (int mf = 0; mf < 4; mf++)
            #pragma unroll
            for (int nf = 0; nf < 2; nf++)
                acc[mf][nf] = __builtin_amdgcn_mfma_f32_16x16x32_f16(
                    af[mf], bf[nf], acc[mf][nf], 0, 0, 0);
        // fused anchor^T emit (z==1, bn==0 only; As holds anchor f16 tile)
        if (z == 1 && bn == 0) {
            const int c = t >> 3, r0 = (t & 7) * 8;
            h8_t h;
            #pragma unroll
            for (int j = 0; j < 8; j++) h[j] = As[(r0 + j) * LDA + c];
            *(h8_t*)(vt + (size_t)(kt + c) * 8192 + bm * 64 + r0) = h;
        }
        __syncthreads();
    }

    #pragma unroll
    for (int mf = 0; mf < 4; mf++)
        #pragma unroll
        for (int nf = 0; nf < 2; nf++)
            #pragma unroll
            for (int r = 0; r < 4; r++) {
                int row = bm * 64 + mf * 16 + lg * 4 + r;
                int col = bn * 128 + w * 32 + nf * 16 + lr;
                C[(size_t)row * 256 + col] = (f16)((acc[mf][nf][r] + bias[col]) * scale);
            }
}

// ------------------------------------------------------------- flash attention
// r4/r7 structure: KVBLK=64, 2 barriers/tile, XOR-swizzled LDS staged linearly
// by global_load_lds with inverse-swizzled global source. No setprio.
__global__ __launch_bounds__(256, 2)
void flash_attn(const f16* __restrict__ Q, const f16* __restrict__ Kc,
                const f16* __restrict__ Vt, f16* __restrict__ OPN,
                float* __restrict__ mpart, float* __restrict__ lpart)
{
    constexpr int D = 256, BK = 64, NK = 8192, SL = 1024, NT = SL / BK;
    __shared__ f16 Ks[BK * D];    // 32 KB
    __shared__ f16 Vs[D * BK];    // 32 KB
    const int t = threadIdx.x, w = t >> 6, l = t & 63;
    const int q = l & 31, hi = l >> 5;
    const int sl = blockIdx.x & 7, qb = blockIdx.x >> 3;
    const int k0b = sl * SL;
    const int qg0 = qb * 128 + w * 32;

    h8_t qf[16];
    {
        const f16* qr = Q + (size_t)(qg0 + q) * D + hi * 8;
        #pragma unroll
        for (int ks = 0; ks < 16; ks++) qf[ks] = *(const h8_t*)(qr + ks * 16);
    }

    const int sK0 = ((t & 31) ^ (t >> 5)) << 3;
    const int sx  = (t & 15) ^ (t >> 4);
    const int dV  = (t >> 4) * 2 + (sx >> 3);
    const int cV  = (sx & 7) << 3;

    auto stageK = [&](int k0) {
        #pragma unroll
        for (int i = 0; i < 8; i++) {
            const f16* g = Kc + (size_t)(k0 + i * 8 + (t >> 5)) * D + (sK0 ^ ((i & 1) << 6));
            llds16(g, &Ks[i * 2048 + w * 512]);
        }
    };
    auto stageV = [&](int k0) {
        #pragma unroll
        for (int i = 0; i < 8; i++) {
            const f16* g = Vt + (size_t)(i * 32 + dV) * NK + k0 + cV;
            llds16(g, &Vs[i * 2048 + w * 512]);
        }
    };

    stageK(k0b); stageV(k0b);
    __syncthreads();

    f16x o[8] = {};
    f16x sa0, sa1;
    float m_run = -1e30f, l_run = 0.f;
    const int rswzK = (q & 15) << 4;
    const int kbase0 = q * 512;
    const int vbase  = (q >> 1) * 256;
    const int vswz   = (q >> 1) << 4;
    const int vcol0  = ((q & 1) << 7) | (hi << 4);

    for (int kv = 0; kv < NT; ++kv) {
        // ---- QK^T (swapped): sa[m=key][n=q]
        #pragma unroll
        for (int r = 0; r < 16; r++) { sa0[r] = 0.f; sa1[r] = 0.f; }
        #pragma unroll
        for (int ks = 0; ks < 16; ks++) {
            const int cb = ((ks * 32) | (hi << 4)) ^ rswzK;
            h8_t a0 = *(const h8_t*)((const char*)Ks + kbase0 + cb);
            h8_t a1 = *(const h8_t*)((const char*)Ks + kbase0 + 16384 + cb);
            sa0 = __builtin_amdgcn_mfma_f32_32x32x16_f16(a0, qf[ks], sa0, 0, 0, 0);
            sa1 = __builtin_amdgcn_mfma_f32_32x32x16_f16(a1, qf[ks], sa1, 0, 0, 0);
        }

        // ---- online softmax (log2 domain), defer-max
        float mt = sa0[0];
        #pragma unroll
        for (int r = 1; r < 16; r++) mt = fmaxf(mt, sa0[r]);
        #pragma unroll
        for (int r = 0; r < 16; r++) mt = fmaxf(mt, sa1[r]);
        mt = fmaxf(mt, __shfl_xor(mt, 32));
        if (!__all(mt <= m_run + 8.0f)) {
            const float mnew = fmaxf(m_run, mt);
            const float corr = exp2f(m_run - mnew);
            #pragma unroll
            for (int r = 0; r < 16; r++) {
                const float c = __shfl(corr, (r & 3) + 8 * (r >> 2) + 4 * hi);
                #pragma unroll
                for (int nb = 0; nb < 8; nb++) o[nb][r] *= c;
            }
            l_run *= corr;
            m_run = mnew;
        }
        float rs = 0.f;
        #pragma unroll
        for (int r = 0; r < 16; r++) { sa0[r] = exp2f(sa0[r] - m_run); rs += sa0[r]; }
        #pragma unroll
        for (int r = 0; r < 16; r++) { sa1[r] = exp2f(sa1[r] - m_run); rs += sa1[r]; }
        rs += __shfl_xor(rs, 32);
        l_run += rs;

        __syncthreads();                              // all waves done reading K
        if (kv + 1 < NT) stageK(k0b + (kv + 1) * BK); // in flight across PV

        // ---- PV: A = packed P, B = V from swizzled LDS
        #pragma unroll
        for (int kb = 0; kb < 2; kb++) {
            const f16x& P = kb ? sa1 : sa0;
            #pragma unroll
            for (int s = 0; s < 2; s++) {
                unsigned int w00 = pk2(P[8*s+0], P[8*s+1]);
                unsigned int w01 = pk2(P[8*s+2], P[8*s+3]);
                unsigned int w10 = pk2(P[8*s+4], P[8*s+5]);
                unsigned int w11 = pk2(P[8*s+6], P[8*s+7]);
                asm volatile("v_permlane32_swap_b32 %0, %1" : "+v"(w00), "+v"(w10));
                asm volatile("v_permlane32_swap_b32 %0, %1" : "+v"(w01), "+v"(w11));
                u4_t up; up[0] = w00; up[1] = w01; up[2] = w10; up[3] = w11;
                const h8_t apv = __builtin_bit_cast(h8_t, up);
                const int S = kb * 2 + s;
                const int cb = (vcol0 | (S << 5)) ^ vswz;
                #pragma unroll
                for (int nb = 0; nb < 8; nb++) {
                    h8_t bf = *(const h8_t*)((const char*)Vs + nb * 4096 + vbase + cb);
                    o[nb] = __builtin_amdgcn_mfma_f32_32x32x16_f16(apv, bf, o[nb], 0, 0, 0);
                }
            }
        }
        __syncthreads();                              // all waves done reading V
        if (kv + 1 < NT) stageV(k0b + (kv + 1) * BK); // in flight across next QK
    }

    #pragma unroll
    for (int r = 0; r < 16; r++) {
        const int qr = (r & 3) + 8 * (r >> 2) + 4 * hi;
        const float linv = 1.0f / __shfl(l_run, qr);
        const size_t rowoff = ((size_t)sl * NK + qg0 + qr) * D;
        #pragma unroll
        for (int nb = 0; nb < 8; nb++)
            OPN[rowoff + nb * 32 + q] = (f16)(o[nb][r] * linv);
    }
    if (hi == 0) {
        mpart[(size_t)sl * NK + qg0 + q] = m_run;
        lpart[(size_t)sl * NK + qg0 + q] = l_run;
    }
}

// ---------------- MLP1 with fused slice-combine staging.
__global__ __launch_bounds__(256)
void mlp1(const float* __restrict__ guess, const f16* __restrict__ OPN,
          const float* __restrict__ mp, const float* __restrict__ lp,
          const f16* __restrict__ W1C, const float* __restrict__ b1,
          const float* __restrict__ a1, f16* __restrict__ H1)
{
    constexpr int LDA = 40, LDB = 40;
    __shared__ f16 As[64 * LDA];
    __shared__ f16 Bs[256 * LDB];
    __shared__ float cn[64][8];
    const int t = threadIdx.x;
    const int w = t >> 6, l = t & 63, lg = l >> 4, lr = l & 15;
    const int m0 = blockIdx.x * 64;

    if (t < 64) {                         // per-row normalized combine coeffs
        float c[8], M = -3.0e38f;
        #pragma unroll
        for (int s = 0; s < 8; s++) { c[s] = mp[s * 8192 + m0 + t]; M = fmaxf(M, c[s]); }
        float wsum = 0.f;
        #pragma unroll
        for (int s = 0; s < 8; s++) { c[s] = exp2f(c[s] - M) * lp[s * 8192 + m0 + t]; wsum += c[s]; }
        const float inv = 1.0f / wsum;
        #pragma unroll
        for (int s = 0; s < 8; s++) cn[t][s] = c[s] * inv;
    }
    __syncthreads();

    const int arow = t >> 2, ac8 = (t & 3) * 8;
    float cnr[8];
    #pragma unroll
    for (int s = 0; s < 8; s++) cnr[s] = cn[arow][s];

    f4_t acc[4][4] = {};
    for (int kt = 0; kt < 512; kt += 32) {
        {   // A tile 64x32
            h8_t h;
            if (kt < 256) {
                const float* Af = guess + (size_t)(m0 + arow) * 256 + kt + ac8;
                f4_t v0 = *(const f4_t*)Af;
                f4_t v1 = *(const f4_t*)(Af + 4);
                h[0]=(f16)v0[0]; h[1]=(f16)v0[1]; h[2]=(f16)v0[2]; h[3]=(f16)v0[3];
                h[4]=(f16)v1[0]; h[5]=(f16)v1[1]; h[6]=(f16)v1[2]; h[7]=(f16)v1[3];
            } else {
                const int d0 = kt - 256 + ac8;
                f4_t v0 = {0.f,0.f,0.f,0.f}, v1 = {0.f,0.f,0.f,0.f};
                #pragma unroll
                for (int s = 0; s < 8; s++) {
                    h8_t ov = *(const h8_t*)(OPN + ((size_t)s * 8192 + m0 + arow) * 256 + d0);
                    const float c = cnr[s];
                    v0[0] += c * (float)ov[0]; v0[1] += c * (float)ov[1];
                    v0[2] += c * (float)ov[2]; v0[3] += c * (float)ov[3];
                    v1[0] += c * (float)ov[4]; v1[1] += c * (float)ov[5];
                    v1[2] += c * (float)ov[6]; v1[3] += c * (float)ov[7];
                }
                h[0]=(f16)v0[0]; h[1]=(f16)v0[1]; h[2]=(f16)v0[2]; h[3]=(f16)v0[3];
                h[4]=(f16)v1[0]; h[5]=(f16)v1[1]; h[6]=(f16)v1[2]; h[7]=(f16)v1[3];
            }
            *(h8_t*)(&As[arow * LDA + ac8]) = h;
        }
        #pragma unroll
        for (int i = 0; i < 4; i++) {      // B tile 256x32
            int s0 = t + i * 256;
            int row = s0 >> 2, c8 = (s0 & 3) * 8;
            *(u4_t*)(&Bs[row * LDB + c8]) =
                *(const u4_t*)(W1C + (size_t)row * 512 + kt + c8);
        }
        __syncthreads();
        h8_t af[4], bf[4];
        #pragma unroll
        for (int mf = 0; mf < 4; mf++)
            af[mf] = *(const h8_t*)(&As[(mf * 16 + lr) * LDA + lg * 8]);
        #pragma unroll
        for (int nf = 0; nf < 4; nf++)
            bf[nf] = *(const h8_t*)(&Bs[(w * 64 + nf * 16 + lr) * LDB + lg * 8]);
        #pragma unroll
        for (int mf = 0; mf < 4; mf++)
            #pragma unroll
            for (int nf = 0; nf < 4; nf++)
                acc[mf][nf] = __builtin_amdgcn_mfma_f32_16x16x32_f16(
                    af[mf], bf[nf], acc[mf][nf], 0, 0, 0);
        __syncthreads();
    }

    const float av = *a1;
    #pragma unroll
    for (int mf = 0; mf < 4; mf++)
        #pragma unroll
        for (int nf = 0; nf < 4; nf++)
            #pragma unroll
            for (int r = 0; r < 4; r++) {
                int row = m0 + mf * 16 + lg * 4 + r;
                int col = w * 64 + nf * 16 + lr;
                float v = acc[mf][nf][r] + b1[col];
                v = v > 0.f ? v : av * v;
                H1[(size_t)row * 256 + col] = (f16)v;
            }
}

// ---------------- MLP2 + final W3 dot. M=8192, N=128, K=256. BM=64 BN=128.
__global__ __launch_bounds__(256)
void mlp2_final(const f16* __restrict__ H1, const f16* __restrict__ W216,
                const float* __restrict__ b2, const float* __restrict__ a2,
                const float* __restrict__ W3, const float* __restrict__ b3,
                float* __restrict__ out)
{
    constexpr int LDA = 40, LDB = 40;
    __shared__ f16 As[64 * LDA];
    __shared__ f16 Bs[128 * LDB];
    __shared__ float part[64][68];
    const int t = threadIdx.x;
    const int w = t >> 6, l = t & 63, lg = l >> 4, lr = l & 15;
    const int m0 = blockIdx.x * 64;
    f4_t acc[4][2] = {};

    for (int kt = 0; kt < 256; kt += 32) {
        const int row = t >> 2, c8 = (t & 3) * 8;
        *(u4_t*)(&As[row * LDA + c8]) =
            *(const u4_t*)(H1 + (size_t)(m0 + row) * 256 + kt + c8);
        *(u4_t*)(&Bs[row * LDB + c8]) =
            *(const u4_t*)(W216 + (size_t)row * 256 + kt + c8);
        *(u4_t*)(&Bs[(row + 64) * LDB + c8]) =
            *(const u4_t*)(W216 + (size_t)(row + 64) * 256 + kt + c8);
        __syncthreads();
        h8_t af[4], bf[2];
        #pragma unroll
        for (int mf = 0; mf < 4; mf++)
            af[mf] = *(const h8_t*)(&As[(mf * 16 + lr) * LDA + lg * 8]);
        #pragma unroll
        for (int nf = 0; nf < 2; nf++)
            bf[nf] = *(const h8_t*)(&Bs[(w * 32 + nf * 16 + lr) * LDB + lg * 8]);
        #pragma unroll
        for (int mf = 0; mf < 4; mf++)
            #pragma unroll
            for (int nf = 0; nf < 2; nf++)
                acc[mf][nf] = __builtin_amdgcn_mfma_f32_16x16x32_f16(
                    af[mf], bf[nf], acc[mf][nf], 0, 0, 0);
        __syncthreads();
    }

    const float av = *a2;
    #pragma unroll
    for (int mf = 0; mf < 4; mf++)
        #pragma unroll
        for (int r = 0; r < 4; r++) {
            float p = 0.f;
            #pragma unroll
            for (int nf = 0; nf < 2; nf++) {
                const int col = w * 32 + nf * 16 + lr;
                float v = acc[mf][nf][r] + b2[col];
                v = v > 0.f ? v : av * v;
                p += v * W3[col];
            }
            part[mf * 16 + lg * 4 + r][w * 16 + lr] = p;
        }
    __syncthreads();
    const int row = t >> 2, q4 = t & 3;
    float s2 = 0.f;
    #pragma unroll
    for (int j = 0; j < 16; j++) s2 += part[row][q4 * 16 + j];
    s2 += __shfl_xor(s2, 1);
    s2 += __shfl_xor(s2, 2);
    if (q4 == 0) out[m0 + row] = s2 + b3[0];
}

// ============================================================================
extern "C" void kernel_launch(void* const* d_in, const int* in_sizes, int n_in,
                              void* d_out, int out_size, void* d_ws, size_t ws_size,
                              hipStream_t stream)
{
    const float* anchor = (const float*)d_in[0];
    const float* guess  = (const float*)d_in[1];
    const float* Wa = (const float*)d_in[2];
    const float* ba = (const float*)d_in[3];
    const float* Wg = (const float*)d_in[4];
    const float* bg = (const float*)d_in[5];
    const float* W1 = (const float*)d_in[6];
    const float* b1 = (const float*)d_in[7];
    const float* a1 = (const float*)d_in[8];
    const float* W2 = (const float*)d_in[9];
    const float* b2 = (const float*)d_in[10];
    const float* a2 = (const float*)d_in[11];
    const float* W3 = (const float*)d_in[12];
    const float* b3 = (const float*)d_in[13];
    float* out = (float*)d_out;
    char* ws = (char*)d_ws;

    const size_t MB = 1u << 20;
    f16* GE16 = (f16*)(ws + 0 * MB);                    // Q (x log2e)   4 MB
    f16* AC16 = (f16*)(ws + 4 * MB);                    // K             4 MB
    f16* VT16 = (f16*)(ws + 8 * MB);                    // V^T           4 MB
    f16* OPN  = (f16*)(ws + 12 * MB);                   // 8x[8192][256] 32 MB
    f16* WA16 = (f16*)(ws + 44 * MB);                   // 128 KB
    f16* WG16 = (f16*)(ws + 44 * MB + 128 * 1024);      // 128 KB
    f16* W1C  = (f16*)(ws + 44 * MB + 256 * 1024);      // 256 KB
    f16* W216 = (f16*)(ws + 44 * MB + 512 * 1024);      // 64 KB
    float* MP = (float*)(ws + 45 * MB);                 // 256 KB
    float* LP = (float*)(ws + 45 * MB + 256 * 1024);    // 256 KB
    f16* H1   = (f16*)(ws + 0 * MB);                    // 4 MB (over GE16, post-flash)

    prep<<<288, 256, 0, stream>>>(Wa, Wg, W1, W2, WA16, WG16, W1C, W216);

    proj_pair<<<dim3(128, 2, 2), 256, 0, stream>>>(
        guess, anchor, WG16, WA16, bg, ba, GE16, AC16, VT16);

    flash_attn<<<512, 256, 0, stream>>>(GE16, AC16, VT16, OPN, MP, LP);

    mlp1<<<128, 256, 0, stream>>>(guess, OPN, MP, LP, W1C, b1, a1, H1);

    mlp2_final<<<128, 256, 0, stream>>>(H1, W216, b2, a2, W3, b3, out);
}

// Round 15
// 158.807 us; speedup vs baseline: 2.8781x; 1.0152x over previous
//
#include <hip/hip_runtime.h>

// Round 15: flash frozen at r7 (byte-identical). Tail optimized:
// (1) proj_pair BN=256 — A staged once (was twice), grid (128,2).
// (2) mlp_fused — MLP1+MLP2+W3-dot in one kernel; H1 lives in LDS
//     ([64][264] f16, 2-way-free banks) instead of an 8MB global round-trip.
// 4 launches total.

typedef _Float16 f16;
typedef _Float16 h8_t  __attribute__((ext_vector_type(8)));
typedef _Float16 h4_t  __attribute__((ext_vector_type(4)));
typedef float    f4_t  __attribute__((ext_vector_type(4)));
typedef float    f16x  __attribute__((ext_vector_type(16)));
typedef unsigned int u4_t  __attribute__((ext_vector_type(4)));

#define LOG2E 1.4426950408889634f

__device__ __forceinline__ void llds16(const f16* g, f16* s) {
    __builtin_amdgcn_global_load_lds(
        (const __attribute__((address_space(1))) void*)g,
        (__attribute__((address_space(3))) void*)s, 16, 0, 0);
}
__device__ __forceinline__ unsigned int pk2(float a, float b) {
    auto h = __builtin_amdgcn_cvt_pkrtz(a, b);
    return __builtin_bit_cast(unsigned int, h);
}

// ---------------- prep: weights f32->f16 (+W1 combine). 288 blocks.
__global__ __launch_bounds__(256)
void prep(const float* __restrict__ Wa, const float* __restrict__ Wg,
          const float* __restrict__ W1, const float* __restrict__ W2,
          f16* __restrict__ oa, f16* __restrict__ og,
          f16* __restrict__ o1c, f16* __restrict__ o2)
{
    int i = blockIdx.x * 256 + threadIdx.x;   // quad index; total 73728
    if (i < 40960) {
        const float* s; f16* d; int off;
        if (i < 16384)      { s = Wa; d = oa; off = i; }
        else if (i < 32768) { s = Wg; d = og; off = i - 16384; }
        else                { s = W2; d = o2; off = i - 32768; }
        f4_t v = ((const f4_t*)s)[off];
        h4_t h;
        h[0]=(f16)v[0]; h[1]=(f16)v[1]; h[2]=(f16)v[2]; h[3]=(f16)v[3];
        ((h4_t*)d)[off] = h;
    } else {
        int off = i - 40960;                  // W1comb [256][512]
        int j = off >> 7, c0 = (off & 127) * 4;
        const float* r = W1 + (size_t)j * 768;
        f4_t v0, v1;
        if (c0 < 256) { v0 = *(const f4_t*)(r + c0); v1 = *(const f4_t*)(r + 512 + c0); }
        else          { v0 = *(const f4_t*)(r + c0); v1 = *(const f4_t*)(r + 256 + c0); }
        h4_t h;
        #pragma unroll
        for (int e = 0; e < 4; e++)
            h[e] = (f16)(c0 < 256 ? v0[e] + v1[e] : v0[e] - v1[e]);
        ((h4_t*)o1c)[off] = h;
    }
}

// ---------------- projections, BN=256 (A staged once); z=1 (anchor) emits VT
__global__ __launch_bounds__(256)
void proj_pair(const float* __restrict__ guess, const float* __restrict__ anchor,
               const f16* __restrict__ WG, const f16* __restrict__ WA,
               const float* __restrict__ bg, const float* __restrict__ ba,
               f16* __restrict__ GE, f16* __restrict__ AC,
               f16* __restrict__ vt)
{
    constexpr int LDA = 40, LDB = 40;
    __shared__ f16 As[64 * LDA];
    __shared__ f16 Bs[256 * LDB];
    const int t = threadIdx.x;
    const int w = t >> 6, l = t & 63, lg = l >> 4, lr = l & 15;
    const int bm = blockIdx.x, z = blockIdx.y;
    const float* A   = z ? anchor : guess;
    const f16*   B   = z ? WA : WG;
    const float* bias= z ? ba : bg;
    const float scale= z ? 1.0f : LOG2E;
    f16* C = z ? AC : GE;
    f4_t acc[4][4] = {};

    for (int kt = 0; kt < 256; kt += 32) {
        {   // A tile 64x32, f32 -> f16
            int row = t >> 2, c8 = (t & 3) * 8;
            const float* Af = A + (size_t)(bm * 64 + row) * 256 + kt + c8;
            f4_t v0 = *(const f4_t*)Af;
            f4_t v1 = *(const f4_t*)(Af + 4);
            h8_t h;
            h[0]=(f16)v0[0]; h[1]=(f16)v0[1]; h[2]=(f16)v0[2]; h[3]=(f16)v0[3];
            h[4]=(f16)v1[0]; h[5]=(f16)v1[1]; h[6]=(f16)v1[2]; h[7]=(f16)v1[3];
            *(h8_t*)(&As[row * LDA + c8]) = h;
        }
        #pragma unroll
        for (int i = 0; i < 4; i++) {  // B tile 256x32
            int s0 = t + i * 256;
            int row = s0 >> 2, c8 = (s0 & 3) * 8;
            *(u4_t*)(&Bs[row * LDB + c8]) =
                *(const u4_t*)(B + (size_t)row * 256 + kt + c8);
        }
        __syncthreads();
        h8_t af[4], bf[4];
        #pragma unroll
        for (int mf = 0; mf < 4; mf++)
            af[mf] = *(const h8_t*)(&As[(mf * 16 + lr) * LDA + lg * 8]);
        #pragma unroll
        for (int nf = 0; nf < 4; nf++)
            bf[nf] = *(const h8_t*)(&Bs[(w * 64 + nf * 16 + lr) * LDB + lg * 8]);
        #pragma unroll
        for (int mf = 0; mf < 4; mf++)
            #pragma unroll
            for (int nf = 0; nf < 4; nf++)
                acc[mf][nf] = __builtin_amdgcn_mfma_f32_16x16x32_f16(
                    af[mf], bf[nf], acc[mf][nf], 0, 0, 0);
        // fused anchor^T emit (z==1; As holds anchor f16 tile)
        if (z == 1) {
            const int c = t >> 3, r0 = (t & 7) * 8;
            h8_t h;
            #pragma unroll
            for (int j = 0; j < 8; j++) h[j] = As[(r0 + j) * LDA + c];
            *(h8_t*)(vt + (size_t)(kt + c) * 8192 + bm * 64 + r0) = h;
        }
        __syncthreads();
    }

    #pragma unroll
    for (int mf = 0; mf < 4; mf++)
        #pragma unroll
        for (int nf = 0; nf < 4; nf++)
            #pragma unroll
            for (int r = 0; r < 4; r++) {
                int row = bm * 64 + mf * 16 + lg * 4 + r;
                int col = w * 64 + nf * 16 + lr;
                C[(size_t)row * 256 + col] = (f16)((acc[mf][nf][r] + bias[col]) * scale);
            }
}

// ------------------------------------------------------------- flash attention
// FROZEN r7 kernel: KVBLK=64, 2 barriers/tile, XOR-swizzled LDS staged linearly
// by global_load_lds with inverse-swizzled global source. No setprio.
__global__ __launch_bounds__(256, 2)
void flash_attn(const f16* __restrict__ Q, const f16* __restrict__ Kc,
                const f16* __restrict__ Vt, f16* __restrict__ OPN,
                float* __restrict__ mpart, float* __restrict__ lpart)
{
    constexpr int D = 256, BK = 64, NK = 8192, SL = 1024, NT = SL / BK;
    __shared__ f16 Ks[BK * D];    // 32 KB
    __shared__ f16 Vs[D * BK];    // 32 KB
    const int t = threadIdx.x, w = t >> 6, l = t & 63;
    const int q = l & 31, hi = l >> 5;
    const int sl = blockIdx.x & 7, qb = blockIdx.x >> 3;
    const int k0b = sl * SL;
    const int qg0 = qb * 128 + w * 32;

    h8_t qf[16];
    {
        const f16* qr = Q + (size_t)(qg0 + q) * D + hi * 8;
        #pragma unroll
        for (int ks = 0; ks < 16; ks++) qf[ks] = *(const h8_t*)(qr + ks * 16);
    }

    const int sK0 = ((t & 31) ^ (t >> 5)) << 3;
    const int sx  = (t & 15) ^ (t >> 4);
    const int dV  = (t >> 4) * 2 + (sx >> 3);
    const int cV  = (sx & 7) << 3;

    auto stageK = [&](int k0) {
        #pragma unroll
        for (int i = 0; i < 8; i++) {
            const f16* g = Kc + (size_t)(k0 + i * 8 + (t >> 5)) * D + (sK0 ^ ((i & 1) << 6));
            llds16(g, &Ks[i * 2048 + w * 512]);
        }
    };
    auto stageV = [&](int k0) {
        #pragma unroll
        for (int i = 0; i < 8; i++) {
            const f16* g = Vt + (size_t)(i * 32 + dV) * NK + k0 + cV;
            llds16(g, &Vs[i * 2048 + w * 512]);
        }
    };

    stageK(k0b); stageV(k0b);
    __syncthreads();

    f16x o[8] = {};
    f16x sa0, sa1;
    float m_run = -1e30f, l_run = 0.f;
    const int rswzK = (q & 15) << 4;
    const int kbase0 = q * 512;
    const int vbase  = (q >> 1) * 256;
    const int vswz   = (q >> 1) << 4;
    const int vcol0  = ((q & 1) << 7) | (hi << 4);

    for (int kv = 0; kv < NT; ++kv) {
        #pragma unroll
        for (int r = 0; r < 16; r++) { sa0[r] = 0.f; sa1[r] = 0.f; }
        #pragma unroll
        for (int ks = 0; ks < 16; ks++) {
            const int cb = ((ks * 32) | (hi << 4)) ^ rswzK;
            h8_t a0 = *(const h8_t*)((const char*)Ks + kbase0 + cb);
            h8_t a1 = *(const h8_t*)((const char*)Ks + kbase0 + 16384 + cb);
            sa0 = __builtin_amdgcn_mfma_f32_32x32x16_f16(a0, qf[ks], sa0, 0, 0, 0);
            sa1 = __builtin_amdgcn_mfma_f32_32x32x16_f16(a1, qf[ks], sa1, 0, 0, 0);
        }

        float mt = sa0[0];
        #pragma unroll
        for (int r = 1; r < 16; r++) mt = fmaxf(mt, sa0[r]);
        #pragma unroll
        for (int r = 0; r < 16; r++) mt = fmaxf(mt, sa1[r]);
        mt = fmaxf(mt, __shfl_xor(mt, 32));
        if (!__all(mt <= m_run + 8.0f)) {
            const float mnew = fmaxf(m_run, mt);
            const float corr = exp2f(m_run - mnew);
            #pragma unroll
            for (int r = 0; r < 16; r++) {
                const float c = __shfl(corr, (r & 3) + 8 * (r >> 2) + 4 * hi);
                #pragma unroll
                for (int nb = 0; nb < 8; nb++) o[nb][r] *= c;
            }
            l_run *= corr;
            m_run = mnew;
        }
        float rs = 0.f;
        #pragma unroll
        for (int r = 0; r < 16; r++) { sa0[r] = exp2f(sa0[r] - m_run); rs += sa0[r]; }
        #pragma unroll
        for (int r = 0; r < 16; r++) { sa1[r] = exp2f(sa1[r] - m_run); rs += sa1[r]; }
        rs += __shfl_xor(rs, 32);
        l_run += rs;

        __syncthreads();
        if (kv + 1 < NT) stageK(k0b + (kv + 1) * BK);

        #pragma unroll
        for (int kb = 0; kb < 2; kb++) {
            const f16x& P = kb ? sa1 : sa0;
            #pragma unroll
            for (int s = 0; s < 2; s++) {
                unsigned int w00 = pk2(P[8*s+0], P[8*s+1]);
                unsigned int w01 = pk2(P[8*s+2], P[8*s+3]);
                unsigned int w10 = pk2(P[8*s+4], P[8*s+5]);
                unsigned int w11 = pk2(P[8*s+6], P[8*s+7]);
                asm volatile("v_permlane32_swap_b32 %0, %1" : "+v"(w00), "+v"(w10));
                asm volatile("v_permlane32_swap_b32 %0, %1" : "+v"(w01), "+v"(w11));
                u4_t up; up[0] = w00; up[1] = w01; up[2] = w10; up[3] = w11;
                const h8_t apv = __builtin_bit_cast(h8_t, up);
                const int S = kb * 2 + s;
                const int cb = (vcol0 | (S << 5)) ^ vswz;
                #pragma unroll
                for (int nb = 0; nb < 8; nb++) {
                    h8_t bf = *(const h8_t*)((const char*)Vs + nb * 4096 + vbase + cb);
                    o[nb] = __builtin_amdgcn_mfma_f32_32x32x16_f16(apv, bf, o[nb], 0, 0, 0);
                }
            }
        }
        __syncthreads();
        if (kv + 1 < NT) stageV(k0b + (kv + 1) * BK);
    }

    #pragma unroll
    for (int r = 0; r < 16; r++) {
        const int qr = (r & 3) + 8 * (r >> 2) + 4 * hi;
        const float linv = 1.0f / __shfl(l_run, qr);
        const size_t rowoff = ((size_t)sl * NK + qg0 + qr) * D;
        #pragma unroll
        for (int nb = 0; nb < 8; nb++)
            OPN[rowoff + nb * 32 + q] = (f16)(o[nb][r] * linv);
    }
    if (hi == 0) {
        mpart[(size_t)sl * NK + qg0 + q] = m_run;
        lpart[(size_t)sl * NK + qg0 + q] = l_run;
    }
}

// ---------------- fused MLP: combine-staged MLP1 -> H1 in LDS -> MLP2 -> W3 dot
// Arena (60KB): phase1 {As 0..5120, Bs1 5120..25600, cn 25600..27648} dies at
// the last phase-1 barrier; then {H1s 0..33792, Bs2 33792..44032, part 44032..}.
__global__ __launch_bounds__(256)
void mlp_fused(const float* __restrict__ guess, const f16* __restrict__ OPN,
               const float* __restrict__ mp, const float* __restrict__ lp,
               const f16* __restrict__ W1C, const float* __restrict__ b1,
               const float* __restrict__ a1, const f16* __restrict__ W216,
               const float* __restrict__ b2, const float* __restrict__ a2,
               const float* __restrict__ W3, const float* __restrict__ b3,
               float* __restrict__ out)
{
    constexpr int LDA = 40, LDB = 40, LDH = 264;
    __shared__ __align__(16) char arena[61440];
    f16* As  = (f16*)arena;                         // [64][40]   phase 1
    f16* Bs1 = (f16*)(arena + 5120);                // [256][40]  phase 1
    float (*cn)[8] = (float(*)[8])(arena + 25600);  // [64][8]    phase 1
    f16* H1s = (f16*)arena;                         // [64][264]  phase 1 epi -> 2
    f16* Bs2 = (f16*)(arena + 33792);               // [128][40]  phase 2
    float (*part)[68] = (float(*)[68])(arena + 44032); // [64][68] phase 2 epi

    const int t = threadIdx.x;
    const int w = t >> 6, l = t & 63, lg = l >> 4, lr = l & 15;
    const int m0 = blockIdx.x * 64;

    if (t < 64) {                         // per-row normalized combine coeffs
        float c[8], M = -3.0e38f;
        #pragma unroll
        for (int s = 0; s < 8; s++) { c[s] = mp[s * 8192 + m0 + t]; M = fmaxf(M, c[s]); }
        float wsum = 0.f;
        #pragma unroll
        for (int s = 0; s < 8; s++) { c[s] = exp2f(c[s] - M) * lp[s * 8192 + m0 + t]; wsum += c[s]; }
        const float inv = 1.0f / wsum;
        #pragma unroll
        for (int s = 0; s < 8; s++) cn[t][s] = c[s] * inv;
    }
    __syncthreads();

    const int arow = t >> 2, ac8 = (t & 3) * 8;
    float cnr[8];
    #pragma unroll
    for (int s = 0; s < 8; s++) cnr[s] = cn[arow][s];

    // ---- phase 1: H1 = PReLU([guess || v] @ W1C^T + b1), K=512
    f4_t acc[4][4] = {};
    for (int kt = 0; kt < 512; kt += 32) {
        {   // A tile 64x32
            h8_t h;
            if (kt < 256) {
                const float* Af = guess + (size_t)(m0 + arow) * 256 + kt + ac8;
                f4_t v0 = *(const f4_t*)Af;
                f4_t v1 = *(const f4_t*)(Af + 4);
                h[0]=(f16)v0[0]; h[1]=(f16)v0[1]; h[2]=(f16)v0[2]; h[3]=(f16)v0[3];
                h[4]=(f16)v1[0]; h[5]=(f16)v1[1]; h[6]=(f16)v1[2]; h[7]=(f16)v1[3];
            } else {
                const int d0 = kt - 256 + ac8;
                f4_t v0 = {0.f,0.f,0.f,0.f}, v1 = {0.f,0.f,0.f,0.f};
                #pragma unroll
                for (int s = 0; s < 8; s++) {
                    h8_t ov = *(const h8_t*)(OPN + ((size_t)s * 8192 + m0 + arow) * 256 + d0);
                    const float c = cnr[s];
                    v0[0] += c * (float)ov[0]; v0[1] += c * (float)ov[1];
                    v0[2] += c * (float)ov[2]; v0[3] += c * (float)ov[3];
                    v1[0] += c * (float)ov[4]; v1[1] += c * (float)ov[5];
                    v1[2] += c * (float)ov[6]; v1[3] += c * (float)ov[7];
                }
                h[0]=(f16)v0[0]; h[1]=(f16)v0[1]; h[2]=(f16)v0[2]; h[3]=(f16)v0[3];
                h[4]=(f16)v1[0]; h[5]=(f16)v1[1]; h[6]=(f16)v1[2]; h[7]=(f16)v1[3];
            }
            *(h8_t*)(&As[arow * LDA + ac8]) = h;
        }
        #pragma unroll
        for (int i = 0; i < 4; i++) {      // B tile 256x32
            int s0 = t + i * 256;
            int row = s0 >> 2, c8 = (s0 & 3) * 8;
            *(u4_t*)(&Bs1[row * LDB + c8]) =
                *(const u4_t*)(W1C + (size_t)row * 512 + kt + c8);
        }
        __syncthreads();
        h8_t af[4], bf[4];
        #pragma unroll
        for (int mf = 0; mf < 4; mf++)
            af[mf] = *(const h8_t*)(&As[(mf * 16 + lr) * LDA + lg * 8]);
        #pragma unroll
        for (int nf = 0; nf < 4; nf++)
            bf[nf] = *(const h8_t*)(&Bs1[(w * 64 + nf * 16 + lr) * LDB + lg * 8]);
        #pragma unroll
        for (int mf = 0; mf < 4; mf++)
            #pragma unroll
            for (int nf = 0; nf < 4; nf++)
                acc[mf][nf] = __builtin_amdgcn_mfma_f32_16x16x32_f16(
                    af[mf], bf[nf], acc[mf][nf], 0, 0, 0);
        __syncthreads();   // last iter: all As/Bs1 reads drained -> overlay safe
    }

    // ---- H1 tile -> LDS (overlays As/Bs1/cn)
    {
        const float av = *a1;
        #pragma unroll
        for (int mf = 0; mf < 4; mf++)
            #pragma unroll
            for (int nf = 0; nf < 4; nf++)
                #pragma unroll
                for (int r = 0; r < 4; r++) {
                    int row = mf * 16 + lg * 4 + r;
                    int col = w * 64 + nf * 16 + lr;
                    float v = acc[mf][nf][r] + b1[col];
                    v = v > 0.f ? v : av * v;
                    H1s[row * LDH + col] = (f16)v;
                }
    }

    // ---- phase 2: H2 = PReLU(H1 @ W2^T + b2), K=256, N=128 (from LDS H1)
    f4_t acc2[4][2] = {};
    for (int kt = 0; kt < 256; kt += 32) {
        const int row = t >> 2, c8 = (t & 3) * 8;
        *(u4_t*)(&Bs2[row * LDB + c8]) =
            *(const u4_t*)(W216 + (size_t)row * 256 + kt + c8);
        *(u4_t*)(&Bs2[(row + 64) * LDB + c8]) =
            *(const u4_t*)(W216 + (size_t)(row + 64) * 256 + kt + c8);
        __syncthreads();   // first iter also publishes H1s writes
        h8_t af[4], bf[2];
        #pragma unroll
        for (int mf = 0; mf < 4; mf++)
            af[mf] = *(const h8_t*)(&H1s[(mf * 16 + lr) * LDH + kt + lg * 8]);
        #pragma unroll
        for (int nf = 0; nf < 2; nf++)
            bf[nf] = *(const h8_t*)(&Bs2[(w * 32 + nf * 16 + lr) * LDB + lg * 8]);
        #pragma unroll
        for (int mf = 0; mf < 4; mf++)
            #pragma unroll
            for (int nf = 0; nf < 2; nf++)
                acc2[mf][nf] = __builtin_amdgcn_mfma_f32_16x16x32_f16(
                    af[mf], bf[nf], acc2[mf][nf], 0, 0, 0);
        __syncthreads();
    }

    // ---- W3-dot epilogue (verified mlp2_final structure)
    const float av2 = *a2;
    #pragma unroll
    for (int mf = 0; mf < 4; mf++)
        #pragma unroll
        for (int r = 0; r < 4; r++) {
            float p = 0.f;
            #pragma unroll
            for (int nf = 0; nf < 2; nf++) {
                const int col = w * 32 + nf * 16 + lr;
                float v = acc2[mf][nf][r] + b2[col];
                v = v > 0.f ? v : av2 * v;
                p += v * W3[col];
            }
            part[mf * 16 + lg * 4 + r][w * 16 + lr] = p;
        }
    __syncthreads();
    const int row = t >> 2, q4 = t & 3;
    float s2 = 0.f;
    #pragma unroll
    for (int j = 0; j < 16; j++) s2 += part[row][q4 * 16 + j];
    s2 += __shfl_xor(s2, 1);
    s2 += __shfl_xor(s2, 2);
    if (q4 == 0) out[m0 + row] = s2 + b3[0];
}

// ============================================================================
extern "C" void kernel_launch(void* const* d_in, const int* in_sizes, int n_in,
                              void* d_out, int out_size, void* d_ws, size_t ws_size,
                              hipStream_t stream)
{
    const float* anchor = (const float*)d_in[0];
    const float* guess  = (const float*)d_in[1];
    const float* Wa = (const float*)d_in[2];
    const float* ba = (const float*)d_in[3];
    const float* Wg = (const float*)d_in[4];
    const float* bg = (const float*)d_in[5];
    const float* W1 = (const float*)d_in[6];
    const float* b1 = (const float*)d_in[7];
    const float* a1 = (const float*)d_in[8];
    const float* W2 = (const float*)d_in[9];
    const float* b2 = (const float*)d_in[10];
    const float* a2 = (const float*)d_in[11];
    const float* W3 = (const float*)d_in[12];
    const float* b3 = (const float*)d_in[13];
    float* out = (float*)d_out;
    char* ws = (char*)d_ws;

    const size_t MB = 1u << 20;
    f16* GE16 = (f16*)(ws + 0 * MB);                    // Q (x log2e)   4 MB
    f16* AC16 = (f16*)(ws + 4 * MB);                    // K             4 MB
    f16* VT16 = (f16*)(ws + 8 * MB);                    // V^T           4 MB
    f16* OPN  = (f16*)(ws + 12 * MB);                   // 8x[8192][256] 32 MB
    f16* WA16 = (f16*)(ws + 44 * MB);                   // 128 KB
    f16* WG16 = (f16*)(ws + 44 * MB + 128 * 1024);      // 128 KB
    f16* W1C  = (f16*)(ws + 44 * MB + 256 * 1024);      // 256 KB
    f16* W216 = (f16*)(ws + 44 * MB + 512 * 1024);      // 64 KB
    float* MP = (float*)(ws + 45 * MB);                 // 256 KB
    float* LP = (float*)(ws + 45 * MB + 256 * 1024);    // 256 KB

    prep<<<288, 256, 0, stream>>>(Wa, Wg, W1, W2, WA16, WG16, W1C, W216);

    proj_pair<<<dim3(128, 2), 256, 0, stream>>>(
        guess, anchor, WG16, WA16, bg, ba, GE16, AC16, VT16);

    flash_attn<<<512, 256, 0, stream>>>(GE16, AC16, VT16, OPN, MP, LP);

    mlp_fused<<<128, 256, 0, stream>>>(guess, OPN, MP, LP, W1C, b1, a1,
                                       W216, b2, a2, W3, b3, out);
}